// Round 15
// baseline (324.561 us; speedup 1.0000x reference)
//
#include <hip/hip_runtime.h>
#include <math.h>

#define NTOK 16384   // B*S
#define DDIM 2048
#define NEXP 64
#define NKQ 16       // K split into 16 slices
#define KSLICE 128   // k per slice (4 ksteps of 32)
#define TPB 64       // tokens per gemm block (4 waves x 16)

typedef __attribute__((ext_vector_type(8))) short bf16x8;
typedef __attribute__((ext_vector_type(4))) float f32x4;

// ws layout (bytes):
//   [0, 516)        aux accumulators (zeroed per call)
//   [1024, 787456)  wp: packed W fragments, ks-major: [64 ks][4 eg][3 part][512 shorts]
//   [1MB, 65MB)     partial logits [16 kq][16384 tok][64 exp] fp32
//   [256MB, 320MB)  kG3 partials clone (scratch)
//   [352MB, +516)   kR6 aux clone (zeroed per call)
//   [353MB, +256KB) kR6 output clone (scratch)

// ---- packed 3-way bf16 split of a float pair via v_cvt_pk_bf16_f32 ----
__device__ __forceinline__ void split3pk(float a, float b,
                                         unsigned &H, unsigned &M, unsigned &L) {
    asm("v_cvt_pk_bf16_f32 %0, %1, %2" : "=v"(H) : "v"(a), "v"(b));
    float ra = a - __builtin_bit_cast(float, H << 16);
    float rb = b - __builtin_bit_cast(float, H & 0xffff0000u);
    asm("v_cvt_pk_bf16_f32 %0, %1, %2" : "=v"(M) : "v"(ra), "v"(rb));
    float sa = ra - __builtin_bit_cast(float, M << 16);
    float sb = rb - __builtin_bit_cast(float, M & 0xffff0000u);
    asm("v_cvt_pk_bf16_f32 %0, %1, %2" : "=v"(L) : "v"(sa), "v"(sb));
}

__device__ __forceinline__ void keepf(float4 &v) {
    asm volatile("" : "+v"(v.x), "+v"(v.y), "+v"(v.z), "+v"(v.w));
}

// ---- pack gate_w into ks-major B-fragment layout (validated) ----
__global__ void k_wpack(const float* __restrict__ gw, unsigned short* __restrict__ wp) {
    int idx = blockIdx.x * 256 + threadIdx.x;   // 16384 threads
    int lane = idx & 63;
    int ks   = (idx >> 6) & 63;
    int eg   = idx >> 12;
    int e  = eg * 16 + (lane & 15);
    int k0 = ks * 32 + (lane >> 4) * 8;
    const float* src = gw + (size_t)e * DDIM + k0;
    uint4 H, M, L;
    split3pk(src[0], src[1], H.x, M.x, L.x);
    split3pk(src[2], src[3], H.y, M.y, L.y);
    split3pk(src[4], src[5], H.z, M.z, L.z);
    split3pk(src[6], src[7], H.w, M.w, L.w);
    size_t fb = ((size_t)ks * 12 + eg * 3) * 512 + lane * 8;   // shorts
    *(uint4*)(wp + fb)        = H;
    *(uint4*)(wp + fb + 512)  = M;
    *(uint4*)(wp + fb + 1024) = L;
}

// ---- production phase 1 (round-11 validated, byte-identical) ----
__global__ __launch_bounds__(256, 2)
void k_gemm(const float* __restrict__ x, const unsigned short* __restrict__ wp,
            float* __restrict__ part) {
    __shared__ __align__(16) char Ws[49152];

    const int tid  = threadIdx.x;
    const int kq   = blockIdx.x & 15;
    const int tok0 = (blockIdx.x >> 4) * TPB;
    const int lane = tid & 63;
    const int wvu  = __builtin_amdgcn_readfirstlane(tid >> 6);
    const int tau  = lane & 15;
    const int kap  = lane >> 4;

    {
        const char* wsrc = (const char*)wp + (size_t)kq * 49152;
        #pragma unroll
        for (int r = 0; r < 12; ++r) {
            const char* g = wsrc + (size_t)(r * 256 + tid) * 16;
            char* l = Ws + (size_t)(r * 256 + wvu * 64) * 16;
            __builtin_amdgcn_global_load_lds(
                (const __attribute__((address_space(1))) void*)g,
                (__attribute__((address_space(3))) void*)l, 16, 0, 0);
        }
    }

    const float* xb = x + (size_t)(tok0 + wvu * 16 + tau) * DDIM
                        + kq * KSLICE + kap * 8;
    float4 x0a = *(const float4*)(xb);
    float4 x0b = *(const float4*)(xb + 4);
    float4 x1a = *(const float4*)(xb + 32);
    float4 x1b = *(const float4*)(xb + 36);
    float4 x2a = *(const float4*)(xb + 64);
    float4 x2b = *(const float4*)(xb + 68);
    float4 x3a = *(const float4*)(xb + 96);
    float4 x3b = *(const float4*)(xb + 100);
    keepf(x0a); keepf(x0b); keepf(x1a); keepf(x1b);
    keepf(x2a); keepf(x2b); keepf(x3a); keepf(x3b);

    __syncthreads();

    f32x4 acc[4];
    #pragma unroll
    for (int eg = 0; eg < 4; ++eg) acc[eg] = (f32x4){0.f, 0.f, 0.f, 0.f};

    #pragma unroll
    for (int ks = 0; ks < 4; ++ks) {
        float4 a = (ks == 0) ? x0a : (ks == 1) ? x1a : (ks == 2) ? x2a : x3a;
        float4 b = (ks == 0) ? x0b : (ks == 1) ? x1b : (ks == 2) ? x2b : x3b;
        uint4 Ah, Am, Al;
        split3pk(a.x, a.y, Ah.x, Am.x, Al.x);
        split3pk(a.z, a.w, Ah.y, Am.y, Al.y);
        split3pk(b.x, b.y, Ah.z, Am.z, Al.z);
        split3pk(b.z, b.w, Ah.w, Am.w, Al.w);
        bf16x8 Ahv = __builtin_bit_cast(bf16x8, Ah);
        bf16x8 Amv = __builtin_bit_cast(bf16x8, Am);
        bf16x8 Alv = __builtin_bit_cast(bf16x8, Al);

        #pragma unroll
        for (int eg = 0; eg < 4; ++eg) {
            const char* wb = Ws + ks * 12288 + eg * 3072 + lane * 16;
            bf16x8 Bh = *(const bf16x8*)(wb);
            bf16x8 Bm = *(const bf16x8*)(wb + 1024);
            bf16x8 Bl = *(const bf16x8*)(wb + 2048);
            acc[eg] = __builtin_amdgcn_mfma_f32_16x16x32_bf16(Ahv, Bh, acc[eg], 0, 0, 0);
            acc[eg] = __builtin_amdgcn_mfma_f32_16x16x32_bf16(Ahv, Bm, acc[eg], 0, 0, 0);
            acc[eg] = __builtin_amdgcn_mfma_f32_16x16x32_bf16(Amv, Bh, acc[eg], 0, 0, 0);
            acc[eg] = __builtin_amdgcn_mfma_f32_16x16x32_bf16(Ahv, Bl, acc[eg], 0, 0, 0);
            acc[eg] = __builtin_amdgcn_mfma_f32_16x16x32_bf16(Alv, Bh, acc[eg], 0, 0, 0);
            acc[eg] = __builtin_amdgcn_mfma_f32_16x16x32_bf16(Amv, Bm, acc[eg], 0, 0, 0);
        }
    }

    float* pb = part + ((size_t)kq * NTOK + tok0 + wvu * 16) * 64;
    #pragma unroll
    for (int eg = 0; eg < 4; ++eg)
        #pragma unroll
        for (int j = 0; j < 4; ++j)
            pb[(kap * 4 + j) * 64 + eg * 16 + tau] = acc[eg][j];
}

// ---- production phase 2 (round-11 validated, byte-identical) ----
__global__ __launch_bounds__(256, 2)
void k_reduce(const float* __restrict__ part, float* __restrict__ out,
              float* __restrict__ gcnt, float* __restrict__ gP,
              float* __restrict__ gz) {
    __shared__ float Ps[NEXP], Cnt[NEXP], Zs;
    const int tid = threadIdx.x;
    if (tid < NEXP) { Ps[tid] = 0.f; Cnt[tid] = 0.f; }
    if (tid == 0) Zs = 0.f;
    __syncthreads();

    const int lane = tid & 63;
    const int wv   = tid >> 6;
    const int t0   = blockIdx.x * 16 + wv * 4;

    float l4[4] = {0.f, 0.f, 0.f, 0.f};
    #pragma unroll
    for (int q = 0; q < NKQ; ++q)
        #pragma unroll
        for (int i = 0; i < 4; ++i)
            l4[i] += part[((size_t)q * NTOK + t0 + i) * 64 + lane];

    float Pacc = 0.f, zacc = 0.f;
    #pragma unroll
    for (int i = 0; i < 4; ++i) {
        float l = l4[i];
        float mx = l;
        #pragma unroll
        for (int off = 32; off > 0; off >>= 1) mx = fmaxf(mx, __shfl_xor(mx, off));
        float s = expf(l - mx);
        float sum = s;
        #pragma unroll
        for (int off = 32; off > 0; off >>= 1) sum += __shfl_xor(sum, off);
        Pacc += s / sum;

        unsigned long long b1 = __ballot(l == mx);
        int i1 = __ffsll(b1) - 1;
        float l2 = (lane == i1) ? -INFINITY : l;
        float m2 = l2;
        #pragma unroll
        for (int off = 32; off > 0; off >>= 1) m2 = fmaxf(m2, __shfl_xor(m2, off));
        unsigned long long b2 = __ballot(l2 == m2);
        int i2 = __ffsll(b2) - 1;

        if (lane == 0) {
            float s2  = expf(m2 - mx);
            float inv = 1.f / (1.f + s2);
            int gt = t0 + i;
            ((float2*)out)[gt]              = make_float2((float)i1, (float)i2);
            ((float2*)(out + 2 * NTOK))[gt] = make_float2(inv, s2 * inv);
            atomicAdd(&Cnt[i1], 1.f);
            atomicAdd(&Cnt[i2], 1.f);
            float lse = mx + logf(sum);
            zacc += lse * lse;
        }
    }
    atomicAdd(&Ps[lane], Pacc);
    if (lane == 0) atomicAdd(&Zs, zacc);
    __syncthreads();

    if (tid < NEXP) {
        atomicAdd(&gcnt[tid], Cnt[tid]);
        atomicAdd(&gP[tid],   Ps[tid]);
    }
    if (tid == 0) atomicAdd(gz, Zs);
}

__global__ void k_final(const float* __restrict__ ws, float* __restrict__ out) {
    int lane = threadIdx.x;
    float v = ws[lane] * ws[64 + lane];
    #pragma unroll
    for (int off = 32; off > 0; off >>= 1) v += __shfl_xor(v, off);
    if (lane == 0) {
        float bal = 64.f * v / (32768.f * 16384.f);
        float z   = ws[128] / 16384.f;
        out[4 * NTOK] = 0.01f * bal + 0.001f * z;
    }
}

// ============ INSTRUMENTATION CLONES (measurement only, scratch output) ======

// kG3: production k_gemm body x3 -> dur = 3G, lands above the 74.5us fills.
__global__ __launch_bounds__(256, 2)
void kG3(const float* __restrict__ x, const unsigned short* __restrict__ wp,
         float* __restrict__ partscr) {
    __shared__ __align__(16) char Ws[49152];
    const int tid  = threadIdx.x;
    const int kq   = blockIdx.x & 15;
    const int tok0 = (blockIdx.x >> 4) * TPB;
    const int lane = tid & 63;
    const int wvu  = __builtin_amdgcn_readfirstlane(tid >> 6);
    const int tau  = lane & 15;
    const int kap  = lane >> 4;
    const float* xb = x + (size_t)(tok0 + wvu * 16 + tau) * DDIM
                        + kq * KSLICE + kap * 8;

    #pragma unroll 1
    for (int it = 0; it < 3; ++it) {
        if (it) __syncthreads();   // prior iter's LDS reads complete
        {
            const char* wsrc = (const char*)wp + (size_t)kq * 49152;
            #pragma unroll
            for (int r = 0; r < 12; ++r) {
                const char* g = wsrc + (size_t)(r * 256 + tid) * 16;
                char* l = Ws + (size_t)(r * 256 + wvu * 64) * 16;
                __builtin_amdgcn_global_load_lds(
                    (const __attribute__((address_space(1))) void*)g,
                    (__attribute__((address_space(3))) void*)l, 16, 0, 0);
            }
        }
        float4 x0a = *(const float4*)(xb);
        float4 x0b = *(const float4*)(xb + 4);
        float4 x1a = *(const float4*)(xb + 32);
        float4 x1b = *(const float4*)(xb + 36);
        float4 x2a = *(const float4*)(xb + 64);
        float4 x2b = *(const float4*)(xb + 68);
        float4 x3a = *(const float4*)(xb + 96);
        float4 x3b = *(const float4*)(xb + 100);
        keepf(x0a); keepf(x0b); keepf(x1a); keepf(x1b);
        keepf(x2a); keepf(x2b); keepf(x3a); keepf(x3b);

        __syncthreads();

        f32x4 acc[4];
        #pragma unroll
        for (int eg = 0; eg < 4; ++eg) acc[eg] = (f32x4){0.f, 0.f, 0.f, 0.f};

        #pragma unroll
        for (int ks = 0; ks < 4; ++ks) {
            float4 a = (ks == 0) ? x0a : (ks == 1) ? x1a : (ks == 2) ? x2a : x3a;
            float4 b = (ks == 0) ? x0b : (ks == 1) ? x1b : (ks == 2) ? x2b : x3b;
            uint4 Ah, Am, Al;
            split3pk(a.x, a.y, Ah.x, Am.x, Al.x);
            split3pk(a.z, a.w, Ah.y, Am.y, Al.y);
            split3pk(b.x, b.y, Ah.z, Am.z, Al.z);
            split3pk(b.z, b.w, Ah.w, Am.w, Al.w);
            bf16x8 Ahv = __builtin_bit_cast(bf16x8, Ah);
            bf16x8 Amv = __builtin_bit_cast(bf16x8, Am);
            bf16x8 Alv = __builtin_bit_cast(bf16x8, Al);

            #pragma unroll
            for (int eg = 0; eg < 4; ++eg) {
                const char* wb = Ws + ks * 12288 + eg * 3072 + lane * 16;
                bf16x8 Bh = *(const bf16x8*)(wb);
                bf16x8 Bm = *(const bf16x8*)(wb + 1024);
                bf16x8 Bl = *(const bf16x8*)(wb + 2048);
                acc[eg] = __builtin_amdgcn_mfma_f32_16x16x32_bf16(Ahv, Bh, acc[eg], 0, 0, 0);
                acc[eg] = __builtin_amdgcn_mfma_f32_16x16x32_bf16(Ahv, Bm, acc[eg], 0, 0, 0);
                acc[eg] = __builtin_amdgcn_mfma_f32_16x16x32_bf16(Amv, Bh, acc[eg], 0, 0, 0);
                acc[eg] = __builtin_amdgcn_mfma_f32_16x16x32_bf16(Ahv, Bl, acc[eg], 0, 0, 0);
                acc[eg] = __builtin_amdgcn_mfma_f32_16x16x32_bf16(Alv, Bh, acc[eg], 0, 0, 0);
                acc[eg] = __builtin_amdgcn_mfma_f32_16x16x32_bf16(Amv, Bm, acc[eg], 0, 0, 0);
            }
        }

        float* pb = partscr + ((size_t)kq * NTOK + tok0 + wvu * 16) * 64;
        #pragma unroll
        for (int eg = 0; eg < 4; ++eg)
            #pragma unroll
            for (int j = 0; j < 4; ++j)
                pb[(kap * 4 + j) * 64 + eg * 16 + tau] = acc[eg][j];
        asm volatile("" ::: "memory");
    }
}

// kR6: production k_reduce body x6 -> dur = 6R.
__global__ __launch_bounds__(256, 2)
void kR6(const float* __restrict__ part, float* __restrict__ outc,
         float* __restrict__ gcnt, float* __restrict__ gP,
         float* __restrict__ gz) {
    __shared__ float Ps[NEXP], Cnt[NEXP], Zs;
    const int tid = threadIdx.x;
    const int lane = tid & 63;
    const int wv   = tid >> 6;
    const int t0   = blockIdx.x * 16 + wv * 4;

    #pragma unroll 1
    for (int it = 0; it < 6; ++it) {
        __syncthreads();
        if (tid < NEXP) { Ps[tid] = 0.f; Cnt[tid] = 0.f; }
        if (tid == 0) Zs = 0.f;
        __syncthreads();

        float l4[4] = {0.f, 0.f, 0.f, 0.f};
        #pragma unroll
        for (int q = 0; q < NKQ; ++q)
            #pragma unroll
            for (int i = 0; i < 4; ++i)
                l4[i] += part[((size_t)q * NTOK + t0 + i) * 64 + lane];

        float Pacc = 0.f, zacc = 0.f;
        #pragma unroll
        for (int i = 0; i < 4; ++i) {
            float l = l4[i];
            float mx = l;
            #pragma unroll
            for (int off = 32; off > 0; off >>= 1) mx = fmaxf(mx, __shfl_xor(mx, off));
            float s = expf(l - mx);
            float sum = s;
            #pragma unroll
            for (int off = 32; off > 0; off >>= 1) sum += __shfl_xor(sum, off);
            Pacc += s / sum;

            unsigned long long b1 = __ballot(l == mx);
            int i1 = __ffsll(b1) - 1;
            float l2 = (lane == i1) ? -INFINITY : l;
            float m2 = l2;
            #pragma unroll
            for (int off = 32; off > 0; off >>= 1) m2 = fmaxf(m2, __shfl_xor(m2, off));
            unsigned long long b2 = __ballot(l2 == m2);
            int i2 = __ffsll(b2) - 1;

            if (lane == 0) {
                float s2  = expf(m2 - mx);
                float inv = 1.f / (1.f + s2);
                int gt = t0 + i;
                ((float2*)outc)[gt]               = make_float2((float)i1, (float)i2);
                ((float2*)(outc + 2 * NTOK))[gt]  = make_float2(inv, s2 * inv);
                atomicAdd(&Cnt[i1], 1.f);
                atomicAdd(&Cnt[i2], 1.f);
                float lse = mx + logf(sum);
                zacc += lse * lse;
            }
        }
        atomicAdd(&Ps[lane], Pacc);
        if (lane == 0) atomicAdd(&Zs, zacc);
        __syncthreads();

        if (tid < NEXP) {
            atomicAdd(&gcnt[tid], Cnt[tid]);
            atomicAdd(&gP[tid],   Ps[tid]);
        }
        if (tid == 0) atomicAdd(gz, Zs);
        asm volatile("" ::: "memory");
    }
}

extern "C" void kernel_launch(void* const* d_in, const int* in_sizes, int n_in,
                              void* d_out, int out_size, void* d_ws, size_t ws_size,
                              hipStream_t stream) {
    const float* x  = (const float*)d_in[0];
    const float* gw = (const float*)d_in[1];
    float* out = (float*)d_out;
    float* wsf = (float*)d_ws;
    unsigned short* wp = (unsigned short*)((char*)d_ws + 1024);
    float* part = (float*)((char*)d_ws + (1 << 20));
    float* partscr = (float*)((char*)d_ws + ((size_t)256 << 20));
    float* auxc    = (float*)((char*)d_ws + ((size_t)352 << 20));
    float* outc    = (float*)((char*)d_ws + ((size_t)353 << 20));

    hipMemsetAsync(d_ws, 0, 516, stream);
    hipMemsetAsync(auxc, 0, 516, stream);

    // ---- production (round-11 validated, unchanged) ----
    k_wpack<<<64, 256, 0, stream>>>(gw, wp);
    k_gemm<<<NKQ * (NTOK / TPB), 256, 0, stream>>>(x, wp, part);
    k_reduce<<<NTOK / 16, 256, 0, stream>>>(part, out, wsf, wsf + 64, wsf + 128);
    k_final<<<1, 64, 0, stream>>>(wsf, out);

    // ---- instrumentation clones (scratch outputs) ----
    kG3<<<NKQ * (NTOK / TPB), 256, 0, stream>>>(x, wp, partscr);
    kR6<<<NTOK / 16, 256, 0, stream>>>(part, outc, auxc, auxc + 64, auxc + 128);
}

// Round 16
// 79.150 us; speedup vs baseline: 4.1006x; 4.1006x over previous
//
#include <hip/hip_runtime.h>
#include <math.h>

#define NTOK 16384   // B*S
#define DDIM 2048
#define NEXP 64
#define NKQ 16       // K split into 16 slices
#define KSLICE 128   // k per slice (4 ksteps of 32)
#define TPB 64       // tokens per gemm block (4 waves x 16)

typedef __attribute__((ext_vector_type(8))) short bf16x8;
typedef __attribute__((ext_vector_type(4))) float f32x4;

// ws layout (bytes):
//   [0, 516)        aux accumulators (zeroed by k_wpack block 0 each call)
//   [1024, 787456)  wp: packed W fragments, ks-major: [64 ks][4 eg][3 part][512 shorts]
//   [1MB, 65MB)     partial logits [16 kq][16384 tok][64 exp] fp32

// ---- packed 3-way bf16 split of a float pair via v_cvt_pk_bf16_f32 ----
__device__ __forceinline__ void split3pk(float a, float b,
                                         unsigned &H, unsigned &M, unsigned &L) {
    asm("v_cvt_pk_bf16_f32 %0, %1, %2" : "=v"(H) : "v"(a), "v"(b));
    float ra = a - __builtin_bit_cast(float, H << 16);
    float rb = b - __builtin_bit_cast(float, H & 0xffff0000u);
    asm("v_cvt_pk_bf16_f32 %0, %1, %2" : "=v"(M) : "v"(ra), "v"(rb));
    float sa = ra - __builtin_bit_cast(float, M << 16);
    float sb = rb - __builtin_bit_cast(float, M & 0xffff0000u);
    asm("v_cvt_pk_bf16_f32 %0, %1, %2" : "=v"(L) : "v"(sa), "v"(sb));
}

__device__ __forceinline__ void keepf(float4 &v) {
    asm volatile("" : "+v"(v.x), "+v"(v.y), "+v"(v.z), "+v"(v.w));
}

// ---- pack gate_w into ks-major B-fragment layout; block 0 zeroes aux ----
__global__ void k_wpack(const float* __restrict__ gw, unsigned short* __restrict__ wp,
                        float* __restrict__ aux) {
    if (blockIdx.x == 0 && threadIdx.x < 132) aux[threadIdx.x] = 0.f;
    int idx = blockIdx.x * 256 + threadIdx.x;   // 16384 threads
    int lane = idx & 63;
    int ks   = (idx >> 6) & 63;
    int eg   = idx >> 12;
    int e  = eg * 16 + (lane & 15);
    int k0 = ks * 32 + (lane >> 4) * 8;
    const float* src = gw + (size_t)e * DDIM + k0;
    uint4 H, M, L;
    split3pk(src[0], src[1], H.x, M.x, L.x);
    split3pk(src[2], src[3], H.y, M.y, L.y);
    split3pk(src[4], src[5], H.z, M.z, L.z);
    split3pk(src[6], src[7], H.w, M.w, L.w);
    size_t fb = ((size_t)ks * 12 + eg * 3) * 512 + lane * 8;   // shorts
    *(uint4*)(wp + fb)        = H;
    *(uint4*)(wp + fb + 512)  = M;
    *(uint4*)(wp + fb + 1024) = L;
}

// ---- phase 1 (round-11 validated, byte-identical): K-sliced GEMM ----
__global__ __launch_bounds__(256, 2)
void k_gemm(const float* __restrict__ x, const unsigned short* __restrict__ wp,
            float* __restrict__ part) {
    __shared__ __align__(16) char Ws[49152];

    const int tid  = threadIdx.x;
    const int kq   = blockIdx.x & 15;
    const int tok0 = (blockIdx.x >> 4) * TPB;
    const int lane = tid & 63;
    const int wvu  = __builtin_amdgcn_readfirstlane(tid >> 6);
    const int tau  = lane & 15;
    const int kap  = lane >> 4;

    {
        const char* wsrc = (const char*)wp + (size_t)kq * 49152;
        #pragma unroll
        for (int r = 0; r < 12; ++r) {
            const char* g = wsrc + (size_t)(r * 256 + tid) * 16;
            char* l = Ws + (size_t)(r * 256 + wvu * 64) * 16;
            __builtin_amdgcn_global_load_lds(
                (const __attribute__((address_space(1))) void*)g,
                (__attribute__((address_space(3))) void*)l, 16, 0, 0);
        }
    }

    const float* xb = x + (size_t)(tok0 + wvu * 16 + tau) * DDIM
                        + kq * KSLICE + kap * 8;
    float4 x0a = *(const float4*)(xb);
    float4 x0b = *(const float4*)(xb + 4);
    float4 x1a = *(const float4*)(xb + 32);
    float4 x1b = *(const float4*)(xb + 36);
    float4 x2a = *(const float4*)(xb + 64);
    float4 x2b = *(const float4*)(xb + 68);
    float4 x3a = *(const float4*)(xb + 96);
    float4 x3b = *(const float4*)(xb + 100);
    keepf(x0a); keepf(x0b); keepf(x1a); keepf(x1b);
    keepf(x2a); keepf(x2b); keepf(x3a); keepf(x3b);

    __syncthreads();

    f32x4 acc[4];
    #pragma unroll
    for (int eg = 0; eg < 4; ++eg) acc[eg] = (f32x4){0.f, 0.f, 0.f, 0.f};

    #pragma unroll
    for (int ks = 0; ks < 4; ++ks) {
        float4 a = (ks == 0) ? x0a : (ks == 1) ? x1a : (ks == 2) ? x2a : x3a;
        float4 b = (ks == 0) ? x0b : (ks == 1) ? x1b : (ks == 2) ? x2b : x3b;
        uint4 Ah, Am, Al;
        split3pk(a.x, a.y, Ah.x, Am.x, Al.x);
        split3pk(a.z, a.w, Ah.y, Am.y, Al.y);
        split3pk(b.x, b.y, Ah.z, Am.z, Al.z);
        split3pk(b.z, b.w, Ah.w, Am.w, Al.w);
        bf16x8 Ahv = __builtin_bit_cast(bf16x8, Ah);
        bf16x8 Amv = __builtin_bit_cast(bf16x8, Am);
        bf16x8 Alv = __builtin_bit_cast(bf16x8, Al);

        #pragma unroll
        for (int eg = 0; eg < 4; ++eg) {
            const char* wb = Ws + ks * 12288 + eg * 3072 + lane * 16;
            bf16x8 Bh = *(const bf16x8*)(wb);
            bf16x8 Bm = *(const bf16x8*)(wb + 1024);
            bf16x8 Bl = *(const bf16x8*)(wb + 2048);
            acc[eg] = __builtin_amdgcn_mfma_f32_16x16x32_bf16(Ahv, Bh, acc[eg], 0, 0, 0);
            acc[eg] = __builtin_amdgcn_mfma_f32_16x16x32_bf16(Ahv, Bm, acc[eg], 0, 0, 0);
            acc[eg] = __builtin_amdgcn_mfma_f32_16x16x32_bf16(Amv, Bh, acc[eg], 0, 0, 0);
            acc[eg] = __builtin_amdgcn_mfma_f32_16x16x32_bf16(Ahv, Bl, acc[eg], 0, 0, 0);
            acc[eg] = __builtin_amdgcn_mfma_f32_16x16x32_bf16(Alv, Bh, acc[eg], 0, 0, 0);
            acc[eg] = __builtin_amdgcn_mfma_f32_16x16x32_bf16(Amv, Bm, acc[eg], 0, 0, 0);
        }
    }

    float* pb = part + ((size_t)kq * NTOK + tok0 + wvu * 16) * 64;
    #pragma unroll
    for (int eg = 0; eg < 4; ++eg)
        #pragma unroll
        for (int j = 0; j < 4; ++j)
            pb[(kap * 4 + j) * 64 + eg * 16 + tau] = acc[eg][j];
}

// ---- phase 2: VECTORIZED deterministic K-reduction + softmax/top-2/aux ----
// lane = (token-group g = lane>>4, expert-quad s = lane&15). Each thread owns
// one token's 4 experts; loads are dwordx4 (wave reads 1KB contiguous per q).
__global__ __launch_bounds__(256, 2)
void k_reduce(const float* __restrict__ part, float* __restrict__ out,
              float* __restrict__ gcnt, float* __restrict__ gP,
              float* __restrict__ gz) {
    __shared__ float Ps[NEXP], Cnt[NEXP], Zs;
    const int tid = threadIdx.x;
    if (tid < NEXP) { Ps[tid] = 0.f; Cnt[tid] = 0.f; }
    if (tid == 0) Zs = 0.f;
    __syncthreads();

    const int lane = tid & 63;
    const int wv   = tid >> 6;
    const int g    = lane >> 4;                  // token within wave
    const int s    = lane & 15;                  // expert quad
    const int t    = blockIdx.x * 16 + wv * 4 + g;
    const int e4   = s * 4;

    // fixed-order (ascending q) sum — bit-identical logits to prior rounds
    f32x4 a = {0.f, 0.f, 0.f, 0.f};
    #pragma unroll
    for (int q = 0; q < NKQ; ++q) {
        const f32x4 v = *(const f32x4*)(part + ((size_t)q * NTOK + t) * 64 + e4);
        a[0] += v[0]; a[1] += v[1]; a[2] += v[2]; a[3] += v[3];
    }

    // local top-2 over the 4 owned experts (strict >, so lowest index on ties)
    float m1 = a[0], m2 = -INFINITY;
    int   i1 = e4,   i2 = NEXP;
    #pragma unroll
    for (int j = 1; j < 4; ++j) {
        float v = a[j]; int idx = e4 + j;
        if (v > m1)      { m2 = m1; i2 = i1; m1 = v; i1 = idx; }
        else if (v > m2) { m2 = v;  i2 = idx; }
    }
    // sorted top-2 merge across the 16-lane group (lowest index on ties)
    #pragma unroll
    for (int off = 1; off < 16; off <<= 1) {
        float n1 = __shfl_xor(m1, off, 16);
        int   j1 = __shfl_xor(i1, off, 16);
        float n2 = __shfl_xor(m2, off, 16);
        int   j2 = __shfl_xor(i2, off, 16);
        bool pwin = (n1 > m1) || (n1 == m1 && j1 < i1);
        float w1 = pwin ? n1 : m1;  int wi1 = pwin ? j1 : i1;
        float c  = pwin ? m1 : n1;  int ci  = pwin ? i1 : j1;   // loser's first
        float ws = pwin ? n2 : m2;  int wsi = pwin ? j2 : i2;   // winner's second
        bool csec = (c > ws) || (c == ws && ci < wsi);
        m1 = w1; i1 = wi1;
        m2 = csec ? c : ws; i2 = csec ? ci : wsi;
    }

    // softmax pieces (m1 is the row max)
    float ex0 = expf(a[0] - m1), ex1 = expf(a[1] - m1);
    float ex2 = expf(a[2] - m1), ex3 = expf(a[3] - m1);
    float sum = (ex0 + ex1) + (ex2 + ex3);
    #pragma unroll
    for (int off = 1; off < 16; off <<= 1) sum += __shfl_xor(sum, off, 16);

    float inv = 1.f / sum;
    atomicAdd(&Ps[e4 + 0], ex0 * inv);
    atomicAdd(&Ps[e4 + 1], ex1 * inv);
    atomicAdd(&Ps[e4 + 2], ex2 * inv);
    atomicAdd(&Ps[e4 + 3], ex3 * inv);

    if (s == 0) {
        float s2  = expf(m2 - m1);
        float w1v = 1.f / (1.f + s2);
        ((float2*)out)[t]              = make_float2((float)i1, (float)i2);
        ((float2*)(out + 2 * NTOK))[t] = make_float2(w1v, s2 * w1v);
        atomicAdd(&Cnt[i1], 1.f);
        atomicAdd(&Cnt[i2], 1.f);
        float lse = m1 + logf(sum);
        atomicAdd(&Zs, lse * lse);
    }
    __syncthreads();

    if (tid < NEXP) {
        atomicAdd(&gcnt[tid], Cnt[tid]);
        atomicAdd(&gP[tid],   Ps[tid]);
    }
    if (tid == 0) atomicAdd(gz, Zs);
}

__global__ void k_final(const float* __restrict__ ws, float* __restrict__ out) {
    int lane = threadIdx.x;
    float v = ws[lane] * ws[64 + lane];
    #pragma unroll
    for (int off = 32; off > 0; off >>= 1) v += __shfl_xor(v, off);
    if (lane == 0) {
        float bal = 64.f * v / (32768.f * 16384.f);
        float z   = ws[128] / 16384.f;
        out[4 * NTOK] = 0.01f * bal + 0.001f * z;
    }
}

extern "C" void kernel_launch(void* const* d_in, const int* in_sizes, int n_in,
                              void* d_out, int out_size, void* d_ws, size_t ws_size,
                              hipStream_t stream) {
    const float* x  = (const float*)d_in[0];
    const float* gw = (const float*)d_in[1];
    float* out = (float*)d_out;
    float* wsf = (float*)d_ws;
    unsigned short* wp = (unsigned short*)((char*)d_ws + 1024);
    float* part = (float*)((char*)d_ws + (1 << 20));

    k_wpack<<<64, 256, 0, stream>>>(gw, wp, wsf);
    k_gemm<<<NKQ * (NTOK / TPB), 256, 0, stream>>>(x, wp, part);
    k_reduce<<<NTOK / 16, 256, 0, stream>>>(part, out, wsf, wsf + 64, wsf + 128);
    k_final<<<1, 64, 0, stream>>>(wsf, out);
}